// Round 3
// 447.706 us; speedup vs baseline: 1.1784x; 1.1784x over previous
//
#include <hip/hip_runtime.h>

#define Nn 8192
#define Ee 8192
#define Hh 256
#define MASK_W 128   // 8192 bits / 64
#define RQ 16
#define NPQ 512      // Nn / RQ  (pq blocks come first in the fused grid)

typedef unsigned long long u64;
// native clang vector — required by __builtin_nontemporal_load
// (HIP's float4 is a struct and is rejected by the builtin)
typedef float nf4 __attribute__((ext_vector_type(4)));

// ---------------------------------------------------------------------------
// Kernel 1: pre — fused preA+preB in ONE workgroup (u -> g dependency handled
// by __syncthreads instead of a second launch). u lives in LDS only.
//   u[k]  = Wc[k,:].v          w2[k] = Wf[k,:].v
//   g[k]  = u[k] + Wx[k,:].u
//   consts[0]=bx.u  consts[1]=beta*(bc.v)+bf.v+bs  consts[2]=sign  consts[3]=beta
// ---------------------------------------------------------------------------
__global__ void __launch_bounds__(256)
pre_kernel(const float* __restrict__ Wc, const float* __restrict__ Wf,
           const float* __restrict__ Wx, const float* __restrict__ v_,
           const float* __restrict__ bc, const float* __restrict__ bf_,
           const float* __restrict__ bx, const float* __restrict__ bs,
           const float* __restrict__ beta, const int* __restrict__ boolen,
           float* __restrict__ w2, float* __restrict__ g,
           float* __restrict__ consts) {
    __shared__ float sv[Hh];
    __shared__ float su[Hh];
    __shared__ float r1[Hh], r2[Hh], r3[Hh];
    const int tid = threadIdx.x;
    sv[tid] = v_[tid];
    __syncthreads();

    const float4* wc4 = reinterpret_cast<const float4*>(Wc + (size_t)tid * Hh);
    const float4* wf4 = reinterpret_cast<const float4*>(Wf + (size_t)tid * Hh);
    const float4* sv4 = reinterpret_cast<const float4*>(sv);
    float a = 0.f, b = 0.f;
#pragma unroll 8
    for (int j = 0; j < Hh / 4; ++j) {
        const float4 w = wc4[j];
        const float4 f = wf4[j];
        const float4 s = sv4[j];
        a = fmaf(w.x, s.x, fmaf(w.y, s.y, fmaf(w.z, s.z, fmaf(w.w, s.w, a))));
        b = fmaf(f.x, s.x, fmaf(f.y, s.y, fmaf(f.z, s.z, fmaf(f.w, s.w, b))));
    }
    su[tid] = a;
    w2[tid] = b;
    __syncthreads();

    const float4* wx4 = reinterpret_cast<const float4*>(Wx + (size_t)tid * Hh);
    const float4* su4 = reinterpret_cast<const float4*>(su);
    float c = a;   // g[k] = u[k] + Wx[k,:].u
#pragma unroll 8
    for (int j = 0; j < Hh / 4; ++j) {
        const float4 w = wx4[j];
        const float4 uu = su4[j];
        c = fmaf(w.x, uu.x, fmaf(w.y, uu.y, fmaf(w.z, uu.z, fmaf(w.w, uu.w, c))));
    }
    g[tid] = c;

    r1[tid] = bc[tid] * sv[tid];
    r2[tid] = bf_[tid] * sv[tid];
    r3[tid] = bx[tid] * a;
    __syncthreads();
    for (int s = 128; s > 0; s >>= 1) {
        if (tid < s) { r1[tid] += r1[tid + s]; r2[tid] += r2[tid + s]; r3[tid] += r3[tid + s]; }
        __syncthreads();
    }
    if (tid == 0) {
        const float be = beta[0];
        consts[0] = r3[0];
        consts[1] = be * r1[0] + r2[0] + bs[0];
        consts[2] = (boolen[0] != 0) ? 1.f : -1.f;
        consts[3] = be;
    }
}

// ---------------------------------------------------------------------------
// Kernel 2 (fused A): blocks [0,NPQ) run the pq GEMM (compute/L2-bound),
// blocks [NPQ, NPQ+4096) run the adj bit-pack (HBM-bound). No inter-block
// dependencies; the two regimes co-schedule so pq hides under pack's HBM
// stream. adj is read nontemporally (single-use 256 MB stream -> evict-first,
// protects the hot Wi/Wj L2 lines during the overlap window).
// Both bodies are byte-identical math to the measured-good R8 kernels.
// ---------------------------------------------------------------------------
__global__ void __launch_bounds__(256)
fusedA_kernel(const float* __restrict__ adj, u64* __restrict__ mask,
              const float* __restrict__ x,
              const float* __restrict__ Wi, const float* __restrict__ Wj,
              const float* __restrict__ bi, const float* __restrict__ bj,
              const float* __restrict__ g, const float* __restrict__ consts,
              float* __restrict__ P, float* __restrict__ Q,
              float* __restrict__ t) {
    __shared__ float xs[RQ][Hh];                 // 16 KB (pack blocks ignore it)
    const int tid = threadIdx.x;

    if (blockIdx.x >= NPQ) {
        // ---------------- pack: one wave per half-row ----------------
        const int wave_id = (blockIdx.x - NPQ) * 4 + (tid >> 6);  // 0..16383
        const int lane = tid & 63;
        const int row  = wave_id >> 1;
        const int half = wave_id & 1;
        const nf4* src = reinterpret_cast<const nf4*>(
            adj + (size_t)row * Nn + half * 4096);

        u64 myword = 0;
#pragma unroll
        for (int i = 0; i < 16; ++i) {
            const nf4 v = __builtin_nontemporal_load(src + i * 64 + lane);
            unsigned int nib = 0;
            nib |= (v.x != 0.f) ? 1u : 0u;
            nib |= (v.y != 0.f) ? 2u : 0u;
            nib |= (v.z != 0.f) ? 4u : 0u;
            nib |= (v.w != 0.f) ? 8u : 0u;
            const unsigned int t1 = __shfl_xor(nib, 1);
            const unsigned int by = nib | (t1 << 4);
            const unsigned int t2 = __shfl_xor(by, 2);
            const unsigned int h16 = by | (t2 << 8);
            const unsigned int t4 = __shfl_xor(h16, 4);
            const unsigned int w32 = h16 | (t4 << 16);
            const unsigned int t8 = __shfl_xor(w32, 8);
            const u64 w64 = (u64)w32 | ((u64)t8 << 32);
            const u64 got = __shfl(w64, (lane & 3) << 4);
            if ((lane >> 2) == i) myword = got;
        }
        mask[(size_t)row * MASK_W + half * 64 + lane] = myword;
        return;
    }

    // ---------------- pq: P = x@Wi+bi, Q = x@Wj+bj, t[n] = x[n].g + c0 ------
    const int base = blockIdx.x * RQ;
    {
        const float4* xv = reinterpret_cast<const float4*>(x + (size_t)base * Hh);
        float4* xd = reinterpret_cast<float4*>(&xs[0][0]);
#pragma unroll
        for (int i = tid; i < 1024; i += 256) xd[i] = xv[i];
    }
    __syncthreads();

    {
        const int wave = tid >> 6;
        const int lane = tid & 63;
        const float c0 = consts[0];
#pragma unroll
        for (int r0 = 0; r0 < 4; ++r0) {
            const int r = wave * 4 + r0;
            float s = 0.f;
#pragma unroll
            for (int i = 0; i < 4; ++i) {
                const int c = lane * 4 + i;
                s = fmaf(xs[r][c], g[c], s);
            }
            for (int off = 32; off > 0; off >>= 1) s += __shfl_down(s, off);
            if (lane == 0) t[base + r] = s + c0;
        }
    }

    float accP[RQ], accQ[RQ];
    const float fbi = bi[tid], fbj = bj[tid];
#pragma unroll
    for (int r = 0; r < RQ; ++r) { accP[r] = fbi; accQ[r] = fbj; }

#pragma unroll 4
    for (int k = 0; k < Hh; ++k) {
        const float wiv = Wi[k * Hh + tid];
        const float wjv = Wj[k * Hh + tid];
#pragma unroll
        for (int r = 0; r < RQ; ++r) {
            accP[r] = fmaf(xs[r][k], wiv, accP[r]);
            accQ[r] = fmaf(xs[r][k], wjv, accQ[r]);
        }
    }
#pragma unroll
    for (int r = 0; r < RQ; ++r) {
        P[(size_t)(base + r) * Hh + tid] = accP[r];
        Q[(size_t)(base + r) * Hh + tid] = accQ[r];
    }
}

// ---------------------------------------------------------------------------
// Kernel 3: per-edge block (identical to measured-good R8 kernel).
// ---------------------------------------------------------------------------
__global__ void edge_kernel(const u64* __restrict__ mask, const int* __restrict__ tei,
                            const float* __restrict__ P, const float* __restrict__ Q,
                            const float* __restrict__ w2, const float* __restrict__ t,
                            const float* __restrict__ consts, float* __restrict__ out) {
    const int e = blockIdx.x;
    const int tid = threadIdx.x;
    const int src = tei[e];
    const int dst = tei[Ee + e];

    __shared__ u64 ms[MASK_W];
    __shared__ u64 md[MASK_W];
    if (tid < MASK_W) ms[tid] = mask[(size_t)src * MASK_W + tid];
    else              md[tid - MASK_W] = mask[(size_t)dst * MASK_W + (tid - MASK_W)];
    __syncthreads();

    float accA = 0.f;
    if (tid < MASK_W) {
        u64 m = ms[tid] & md[tid];
        while (m) {
            const int b = __builtin_ctzll(m);
            accA += t[tid * 64 + b];
            m &= m - 1;
        }
    }
    const float r = P[(size_t)src * Hh + tid] + Q[(size_t)dst * Hh + tid];
    float accB = (r > 0.f) ? r * w2[tid] : 0.f;

    for (int off = 32; off > 0; off >>= 1) {
        accA += __shfl_down(accA, off);
        accB += __shfl_down(accB, off);
    }
    __shared__ float wA[4], wB[4];
    const int wave = tid >> 6;
    if ((tid & 63) == 0) { wA[wave] = accA; wB[wave] = accB; }
    __syncthreads();
    if (tid == 0) {
        const float sA = wA[0] + wA[1] + wA[2] + wA[3];
        const float sB = wB[0] + wB[1] + wB[2] + wB[3];
        const float be = consts[3];
        const float sgn = consts[2];
        const float s = be * sA + sB + consts[1];
        const float m = -sgn * s;
        const float res = fmaxf(m, 0.f) + log1pf(expf(-fabsf(m)));
        out[e] = res;
    }
}

extern "C" void kernel_launch(void* const* d_in, const int* in_sizes, int n_in,
                              void* d_out, int out_size, void* d_ws, size_t ws_size,
                              hipStream_t stream) {
    const float* x     = (const float*)d_in[0];
    const float* adj   = (const float*)d_in[1];
    const int*   tei   = (const int*)d_in[2];
    const float* Wx    = (const float*)d_in[3];
    const float* bx    = (const float*)d_in[4];
    const float* Wc    = (const float*)d_in[5];
    const float* bc    = (const float*)d_in[6];
    const float* Wi    = (const float*)d_in[7];
    const float* bi    = (const float*)d_in[8];
    const float* Wj    = (const float*)d_in[9];
    const float* bj    = (const float*)d_in[10];
    const float* Wf    = (const float*)d_in[11];
    const float* bf_   = (const float*)d_in[12];
    const float* v_    = (const float*)d_in[13];
    const float* bs    = (const float*)d_in[14];
    const float* beta  = (const float*)d_in[15];
    const int*   booln = (const int*)d_in[16];
    float* out = (float*)d_out;

    // workspace layout (fp32 elements)
    float* w2     = (float*)d_ws;                // 256
    float* g      = w2 + 256;                    // 256
    float* consts = g + 256;                     // 8 (padded)
    float* t      = consts + 8;                  // 8192
    float* P      = t + 8192;                    // 8192*256 = 8 MB
    float* Q      = P + (size_t)Nn * Hh;         // 8 MB
    u64*   mask   = (u64*)(Q + (size_t)Nn * Hh); // 8192*128 u64 = 8 MB
    // total ~25 MB << ws_size

    pre_kernel<<<1, 256, 0, stream>>>(Wc, Wf, Wx, v_, bc, bf_, bx, bs, beta,
                                      booln, w2, g, consts);
    fusedA_kernel<<<NPQ + (Nn * 2) / 4, 256, 0, stream>>>(adj, mask, x, Wi, Wj,
                                                          bi, bj, g, consts,
                                                          P, Q, t);
    edge_kernel<<<Ee, 256, 0, stream>>>(mask, tei, P, Q, w2, t, consts, out);
}

// Round 4
// 428.770 us; speedup vs baseline: 1.2304x; 1.0442x over previous
//
#include <hip/hip_runtime.h>

#define Nn 8192
#define Ee 8192
#define Hh 256
#define MASK_W 128   // 8192 bits / 64
#define RQ 16
#define NPQ 512      // Nn / RQ  (pq blocks come first in the fused grid)

typedef unsigned long long u64;
// native clang vector — required by __builtin_nontemporal_load
// (HIP's float4 is a struct and is rejected by the builtin)
typedef float nf4 __attribute__((ext_vector_type(4)));

// ---------------------------------------------------------------------------
// Kernel 1 (fused A): 2-kernel structure — the old `pre` kernel is dissolved:
//   * every pq block redundantly recomputes u = Wc.v and g = u + Wx.u
//     in-block (bit-identical arithmetic order to the old pre_kernel), since
//     Wc/Wx/v (513 KB) are L2-resident and the +512 FMA/thread hides under
//     the concurrent pack HBM stream. This removes the single-CU pre kernel
//     (~10 us: one workgroup streaming 768 KB) and one launch gap.
//   * block 0 additionally computes w2 = Wf.v and consts[1..3] (only needed
//     by edge_kernel, which runs after this kernel completes).
// Blocks [0,NPQ) run pq (compute/L2-bound); blocks [NPQ, NPQ+4096) run the
// adj bit-pack (HBM-bound). No inter-block dependencies.
// ---------------------------------------------------------------------------
__global__ void __launch_bounds__(256)
fusedA_kernel(const float* __restrict__ adj, u64* __restrict__ mask,
              const float* __restrict__ x,
              const float* __restrict__ Wi, const float* __restrict__ Wj,
              const float* __restrict__ bi, const float* __restrict__ bj,
              const float* __restrict__ Wc, const float* __restrict__ Wx,
              const float* __restrict__ Wf, const float* __restrict__ v_,
              const float* __restrict__ bx, const float* __restrict__ bc,
              const float* __restrict__ bf_, const float* __restrict__ bs,
              const float* __restrict__ beta, const int* __restrict__ boolen,
              float* __restrict__ w2, float* __restrict__ consts,
              float* __restrict__ P, float* __restrict__ Q,
              float* __restrict__ t) {
    __shared__ float xs[RQ][Hh];                 // 16 KB (pack blocks ignore it)
    __shared__ float sg[Hh];                     // 1 KB — g persists into t-loop
    const int tid = threadIdx.x;

    if (blockIdx.x >= NPQ) {
        // ---------------- pack: one wave per half-row ----------------
        const int wave_id = (blockIdx.x - NPQ) * 4 + (tid >> 6);  // 0..16383
        const int lane = tid & 63;
        const int row  = wave_id >> 1;
        const int half = wave_id & 1;
        const nf4* src = reinterpret_cast<const nf4*>(
            adj + (size_t)row * Nn + half * 4096);

        u64 myword = 0;
#pragma unroll
        for (int i = 0; i < 16; ++i) {
            const nf4 v = __builtin_nontemporal_load(src + i * 64 + lane);
            unsigned int nib = 0;
            nib |= (v.x != 0.f) ? 1u : 0u;
            nib |= (v.y != 0.f) ? 2u : 0u;
            nib |= (v.z != 0.f) ? 4u : 0u;
            nib |= (v.w != 0.f) ? 8u : 0u;
            const unsigned int t1 = __shfl_xor(nib, 1);
            const unsigned int by = nib | (t1 << 4);
            const unsigned int t2 = __shfl_xor(by, 2);
            const unsigned int h16 = by | (t2 << 8);
            const unsigned int t4 = __shfl_xor(h16, 4);
            const unsigned int w32 = h16 | (t4 << 16);
            const unsigned int t8 = __shfl_xor(w32, 8);
            const u64 w64 = (u64)w32 | ((u64)t8 << 32);
            const u64 got = __shfl(w64, (lane & 3) << 4);
            if ((lane >> 2) == i) myword = got;
        }
        mask[(size_t)row * MASK_W + half * 64 + lane] = myword;
        return;
    }

    // ================= pq block =================
    // ---- phase 1: replicate old pre_kernel (scratch aliases xs rows,
    //      which are overwritten later; sg persists) ----
    float* sv = xs[0];
    float* su = xs[1];
    float* r3 = xs[2];
    float* r1 = xs[3];
    float* r2 = xs[4];
    const bool blk0 = (blockIdx.x == 0);

    sv[tid] = v_[tid];
    __syncthreads();

    float a = 0.f, b = 0.f;
    {
        const float4* wc4 = reinterpret_cast<const float4*>(Wc + (size_t)tid * Hh);
        const float4* sv4 = reinterpret_cast<const float4*>(sv);
        if (blk0) {
            const float4* wf4 = reinterpret_cast<const float4*>(Wf + (size_t)tid * Hh);
#pragma unroll 8
            for (int j = 0; j < Hh / 4; ++j) {
                const float4 w = wc4[j];
                const float4 f = wf4[j];
                const float4 s = sv4[j];
                a = fmaf(w.x, s.x, fmaf(w.y, s.y, fmaf(w.z, s.z, fmaf(w.w, s.w, a))));
                b = fmaf(f.x, s.x, fmaf(f.y, s.y, fmaf(f.z, s.z, fmaf(f.w, s.w, b))));
            }
        } else {
#pragma unroll 8
            for (int j = 0; j < Hh / 4; ++j) {
                const float4 w = wc4[j];
                const float4 s = sv4[j];
                a = fmaf(w.x, s.x, fmaf(w.y, s.y, fmaf(w.z, s.z, fmaf(w.w, s.w, a))));
            }
        }
    }
    su[tid] = a;
    if (blk0) w2[tid] = b;
    __syncthreads();

    {
        const float4* wx4 = reinterpret_cast<const float4*>(Wx + (size_t)tid * Hh);
        const float4* su4 = reinterpret_cast<const float4*>(su);
        float c = a;   // g[k] = u[k] + Wx[k,:].u
#pragma unroll 8
        for (int j = 0; j < Hh / 4; ++j) {
            const float4 w = wx4[j];
            const float4 uu = su4[j];
            c = fmaf(w.x, uu.x, fmaf(w.y, uu.y, fmaf(w.z, uu.z, fmaf(w.w, uu.w, c))));
        }
        sg[tid] = c;
    }

    r3[tid] = bx[tid] * a;
    if (blk0) { r1[tid] = bc[tid] * sv[tid]; r2[tid] = bf_[tid] * sv[tid]; }
    __syncthreads();
    for (int s = 128; s > 0; s >>= 1) {
        if (tid < s) {
            r3[tid] += r3[tid + s];
            if (blk0) { r1[tid] += r1[tid + s]; r2[tid] += r2[tid + s]; }
        }
        __syncthreads();
    }
    const float c0 = r3[0];
    if (blk0 && tid == 0) {
        const float be = beta[0];
        consts[1] = be * r1[0] + r2[0] + bs[0];
        consts[2] = (boolen[0] != 0) ? 1.f : -1.f;
        consts[3] = be;
    }
    __syncthreads();   // scratch (xs rows) free for reuse only after this

    // ---- phase 2: pq (identical to measured-good kernel) ----
    const int base = blockIdx.x * RQ;
    {
        const float4* xv = reinterpret_cast<const float4*>(x + (size_t)base * Hh);
        float4* xd = reinterpret_cast<float4*>(&xs[0][0]);
#pragma unroll
        for (int i = tid; i < 1024; i += 256) xd[i] = xv[i];
    }
    __syncthreads();

    {
        const int wave = tid >> 6;
        const int lane = tid & 63;
#pragma unroll
        for (int r0 = 0; r0 < 4; ++r0) {
            const int r = wave * 4 + r0;
            float s = 0.f;
#pragma unroll
            for (int i = 0; i < 4; ++i) {
                const int c = lane * 4 + i;
                s = fmaf(xs[r][c], sg[c], s);
            }
            for (int off = 32; off > 0; off >>= 1) s += __shfl_down(s, off);
            if (lane == 0) t[base + r] = s + c0;
        }
    }

    float accP[RQ], accQ[RQ];
    const float fbi = bi[tid], fbj = bj[tid];
#pragma unroll
    for (int r = 0; r < RQ; ++r) { accP[r] = fbi; accQ[r] = fbj; }

#pragma unroll 4
    for (int k = 0; k < Hh; ++k) {
        const float wiv = Wi[k * Hh + tid];
        const float wjv = Wj[k * Hh + tid];
#pragma unroll
        for (int r = 0; r < RQ; ++r) {
            accP[r] = fmaf(xs[r][k], wiv, accP[r]);
            accQ[r] = fmaf(xs[r][k], wjv, accQ[r]);
        }
    }
#pragma unroll
    for (int r = 0; r < RQ; ++r) {
        P[(size_t)(base + r) * Hh + tid] = accP[r];
        Q[(size_t)(base + r) * Hh + tid] = accQ[r];
    }
}

// ---------------------------------------------------------------------------
// Kernel 2: per-edge block (identical to measured-good kernel).
// ---------------------------------------------------------------------------
__global__ void edge_kernel(const u64* __restrict__ mask, const int* __restrict__ tei,
                            const float* __restrict__ P, const float* __restrict__ Q,
                            const float* __restrict__ w2, const float* __restrict__ t,
                            const float* __restrict__ consts, float* __restrict__ out) {
    const int e = blockIdx.x;
    const int tid = threadIdx.x;
    const int src = tei[e];
    const int dst = tei[Ee + e];

    __shared__ u64 ms[MASK_W];
    __shared__ u64 md[MASK_W];
    if (tid < MASK_W) ms[tid] = mask[(size_t)src * MASK_W + tid];
    else              md[tid - MASK_W] = mask[(size_t)dst * MASK_W + (tid - MASK_W)];
    __syncthreads();

    float accA = 0.f;
    if (tid < MASK_W) {
        u64 m = ms[tid] & md[tid];
        while (m) {
            const int b = __builtin_ctzll(m);
            accA += t[tid * 64 + b];
            m &= m - 1;
        }
    }
    const float r = P[(size_t)src * Hh + tid] + Q[(size_t)dst * Hh + tid];
    float accB = (r > 0.f) ? r * w2[tid] : 0.f;

    for (int off = 32; off > 0; off >>= 1) {
        accA += __shfl_down(accA, off);
        accB += __shfl_down(accB, off);
    }
    __shared__ float wA[4], wB[4];
    const int wave = tid >> 6;
    if ((tid & 63) == 0) { wA[wave] = accA; wB[wave] = accB; }
    __syncthreads();
    if (tid == 0) {
        const float sA = wA[0] + wA[1] + wA[2] + wA[3];
        const float sB = wB[0] + wB[1] + wB[2] + wB[3];
        const float be = consts[3];
        const float sgn = consts[2];
        const float s = be * sA + sB + consts[1];
        const float m = -sgn * s;
        const float res = fmaxf(m, 0.f) + log1pf(expf(-fabsf(m)));
        out[e] = res;
    }
}

extern "C" void kernel_launch(void* const* d_in, const int* in_sizes, int n_in,
                              void* d_out, int out_size, void* d_ws, size_t ws_size,
                              hipStream_t stream) {
    const float* x     = (const float*)d_in[0];
    const float* adj   = (const float*)d_in[1];
    const int*   tei   = (const int*)d_in[2];
    const float* Wx    = (const float*)d_in[3];
    const float* bx    = (const float*)d_in[4];
    const float* Wc    = (const float*)d_in[5];
    const float* bc    = (const float*)d_in[6];
    const float* Wi    = (const float*)d_in[7];
    const float* bi    = (const float*)d_in[8];
    const float* Wj    = (const float*)d_in[9];
    const float* bj    = (const float*)d_in[10];
    const float* Wf    = (const float*)d_in[11];
    const float* bf_   = (const float*)d_in[12];
    const float* v_    = (const float*)d_in[13];
    const float* bs    = (const float*)d_in[14];
    const float* beta  = (const float*)d_in[15];
    const int*   booln = (const int*)d_in[16];
    float* out = (float*)d_out;

    // workspace layout (fp32 elements) — offsets kept from R3 (g slot unused)
    float* w2     = (float*)d_ws;                // 256
    float* g      = w2 + 256;                    // 256 (reserved, unused)
    float* consts = g + 256;                     // 8 (padded)
    float* t      = consts + 8;                  // 8192
    float* P      = t + 8192;                    // 8192*256 = 8 MB
    float* Q      = P + (size_t)Nn * Hh;         // 8 MB
    u64*   mask   = (u64*)(Q + (size_t)Nn * Hh); // 8192*128 u64 = 8 MB
    (void)g;
    // total ~25 MB << ws_size

    fusedA_kernel<<<NPQ + (Nn * 2) / 4, 256, 0, stream>>>(
        adj, mask, x, Wi, Wj, bi, bj, Wc, Wx, Wf, v_, bx, bc, bf_, bs, beta,
        booln, w2, consts, P, Q, t);
    edge_kernel<<<Ee, 256, 0, stream>>>(mask, tei, P, Q, w2, t, consts, out);
}